// Round 7
// baseline (367.230 us; speedup 1.0000x reference)
//
#include <hip/hip_runtime.h>
#include <hip/hip_bf16.h>

#define SEQ   2048
#define BATCH 2
#define NH    16
#define HD    64
#define DM    1024

typedef unsigned short u16;
typedef unsigned int   u32;
typedef __attribute__((ext_vector_type(8))) short bf8;   // 8 bf16 in 4 VGPRs
typedef __attribute__((ext_vector_type(4))) float f4;

__device__ inline u16 f2bf(float f) {                    // round-to-nearest-even
    u32 u = __builtin_bit_cast(u32, f);
    return (u16)((u + 0x7FFFu + ((u >> 16) & 1u)) >> 16);
}

__device__ inline f4 MFMA(bf8 a, bf8 b, f4 c) {
    return __builtin_amdgcn_mfma_f32_16x16x32_bf16(a, b, c, 0, 0, 0);
}

// async global->LDS, 16B per lane (m97 lever)
__device__ inline void gload16(const u16* g, u16* l) {
    __builtin_amdgcn_global_load_lds(
        (const __attribute__((address_space(1))) unsigned int*)(const void*)g,
        (__attribute__((address_space(3))) unsigned int*)(void*)l, 16, 0, 0);
}

// ---------------------------------------------------------------------------
// fused fp32 -> bf16 cast for x, W_qkv, W_out
// ---------------------------------------------------------------------------
#define N4_X  1048576
#define N4_WQ 786432
#define N4_WO 262144
__global__ __launch_bounds__(256) void cast_all(const float* __restrict__ x,
                                                const float* __restrict__ wq,
                                                const float* __restrict__ wo,
                                                u16* __restrict__ xb,
                                                u16* __restrict__ wqb,
                                                u16* __restrict__ wob) {
    const int i = blockIdx.x * 256 + threadIdx.x;
    const float* src;
    u16* dst;
    int j;
    if (i < N4_X)                { src = x;  dst = xb;  j = i; }
    else if (i < N4_X + N4_WQ)   { src = wq; dst = wqb; j = i - N4_X; }
    else                         { src = wo; dst = wob; j = i - N4_X - N4_WQ; }
    const float4 v = ((const float4*)src)[j];
    ushort4 o;
    o.x = f2bf(v.x); o.y = f2bf(v.y); o.z = f2bf(v.z); o.w = f2bf(v.w);
    ((ushort4*)dst)[j] = o;
}

// ---------------------------------------------------------------------------
// bf16 MFMA GEMM (m97 structure): 128x128 tile, 4 waves, 4x4 frags 16x16x32,
// BK=32, unpadded [128][32] LDS via global_load_lds dwordx4.
// MODE 0: qkv epilogue (scatter bf16 into q/k/v [B,H,S,hd]); MODE 1: fp32 out.
// ---------------------------------------------------------------------------
template<int MODE>
__global__ __launch_bounds__(256) void gemm_bf16(const u16* __restrict__ A,
                                                 const u16* __restrict__ Bm,
                                                 const float* __restrict__ bias,
                                                 u16* __restrict__ q_o,
                                                 u16* __restrict__ k_o,
                                                 u16* __restrict__ v_o,
                                                 float* __restrict__ f_o) {
    __shared__ __align__(16) u16 Al[128 * 32];
    __shared__ __align__(16) u16 Bl[128 * 32];
    const int t  = threadIdx.x;
    const int l  = t & 63, w = t >> 6;
    const int n0 = blockIdx.x * 128, m0 = blockIdx.y * 128;
    const int wr = w >> 1, wc = w & 1;
    const int lr16 = l & 15, lg = l >> 4;

    const f4 zf = {0.f, 0.f, 0.f, 0.f};
    f4 acc[4][4];
#pragma unroll
    for (int m = 0; m < 4; ++m)
#pragma unroll
        for (int n = 0; n < 4; ++n) acc[m][n] = zf;

    const int rw = t >> 2;
    const int kc = t & 3;

    for (int k0 = 0; k0 < DM; k0 += 32) {
        __syncthreads();
        gload16(&A[(size_t)(m0 + rw) * DM + k0 + kc * 8],       &Al[rw * 32 + kc * 8]);
        gload16(&A[(size_t)(m0 + 64 + rw) * DM + k0 + kc * 8],  &Al[(64 + rw) * 32 + kc * 8]);
        gload16(&Bm[(size_t)(n0 + rw) * DM + k0 + kc * 8],      &Bl[rw * 32 + kc * 8]);
        gload16(&Bm[(size_t)(n0 + 64 + rw) * DM + k0 + kc * 8], &Bl[(64 + rw) * 32 + kc * 8]);
        __syncthreads();
        bf8 af[4], bfr[4];
#pragma unroll
        for (int m = 0; m < 4; ++m)
            af[m] = *(const bf8*)&Al[(wr * 64 + m * 16 + lr16) * 32 + lg * 8];
#pragma unroll
        for (int n = 0; n < 4; ++n)
            bfr[n] = *(const bf8*)&Bl[(wc * 64 + n * 16 + lr16) * 32 + lg * 8];
        __builtin_amdgcn_s_setprio(1);
#pragma unroll
        for (int m = 0; m < 4; ++m)
#pragma unroll
            for (int n = 0; n < 4; ++n)
                acc[m][n] = MFMA(af[m], bfr[n], acc[m][n]);
        __builtin_amdgcn_s_setprio(0);
    }

#pragma unroll
    for (int m = 0; m < 4; ++m)
#pragma unroll
        for (int n = 0; n < 4; ++n)
#pragma unroll
            for (int r = 0; r < 4; ++r) {
                const int M = m0 + wr * 64 + m * 16 + lg * 4 + r;
                const int N = n0 + wc * 64 + n * 16 + lr16;
                const float val = acc[m][n][r] + bias[N];
                if (MODE == 0) {
                    const int b = M >> 11, s = M & (SEQ - 1);
                    const int h = N / 192, f = N % 192;
                    const int seg = f >> 6, c = f & 63;
                    u16* dst = (seg == 0) ? q_o : ((seg == 1) ? k_o : v_o);
                    dst[(((size_t)(b * NH + h)) * SEQ + s) * HD + c] = f2bf(val);
                } else {
                    f_o[(size_t)M * DM + N] = val;
                }
            }
}

// ---------------------------------------------------------------------------
// V transpose: v [BH][S][64] -> vt [BH][64][S]
// ---------------------------------------------------------------------------
__global__ __launch_bounds__(256) void v_transpose(const u16* __restrict__ v,
                                                   u16* __restrict__ vt) {
    __shared__ u16 tl[64][65];
    const int t  = threadIdx.x;
    const int s0 = blockIdx.x * 64;
    const int bh = blockIdx.y;
    const u16* src = v + ((size_t)bh * SEQ + s0) * HD;
#pragma unroll
    for (int i = 0; i < 2; ++i) {
        const int c = i * 256 + t, s = c >> 3, cc = c & 7;
        const float4 d = *(const float4*)&src[s * HD + cc * 8];
        const u16* dp = (const u16*)&d;
#pragma unroll
        for (int j = 0; j < 8; ++j) tl[s][cc * 8 + j] = dp[j];
    }
    __syncthreads();
    u16* dst = vt + (size_t)bh * HD * SEQ + s0;
#pragma unroll
    for (int i = 0; i < 2; ++i) {
        const int c = i * 256 + t, dim = c >> 3, sc = c & 7;
        __align__(16) u16 tmp[8];
#pragma unroll
        for (int j = 0; j < 8; ++j) tmp[j] = tl[sc * 8 + j][dim];
        *(float4*)&dst[(size_t)dim * SEQ + sc * 8] = *(const float4*)tmp;
    }
}

// ---------------------------------------------------------------------------
// MFMA flash attention v3: 128 q-rows/block, 4 waves x 32 q-rows (2 m-blocks),
// 64-key tiles, K/V double-buffered (1 barrier/tile), log2-domain softmax,
// lane-partial l, fully-deferred max (lane-local trigger, THR=8 in log2),
// XCD-locality block linearization, LDS-staged epilogue.
// ---------------------------------------------------------------------------
#define KS 72
#define QW 32
__global__ __launch_bounds__(256) void flash_attn(const u16* __restrict__ qg,
                                                  const u16* __restrict__ kg,
                                                  const u16* __restrict__ vtg,
                                                  const float* __restrict__ mask,
                                                  u16* __restrict__ og) {
    __shared__ __align__(16) u16 Kl[2][64 * KS];
    __shared__ __align__(16) u16 Vl[2][64 * KS];
    __shared__ __align__(16) u16 Pl[4 * QW * KS];   // wave-private P; reused as O-stage [128][KS]
    const int t = threadIdx.x, l = t & 63, w = t >> 6;
    const int lr16 = l & 15, lg = l >> 4;
    // block id = qt*32 + bh  ->  same-(b,h) blocks land on one XCD (ids = mod 8)
    const int bx = blockIdx.x;
    const int qt = bx >> 5, bh = bx & 31;
    const int h = bh & 15, b = bh >> 4;
    const int q0 = qt * 128;
    const int qbase = q0 + w * QW;

    const float C1 = 0.18033688011f;   // 0.125 * log2(e)
    const float L2E = 1.44269504089f;

    bf8 qf[2][2];
#pragma unroll
    for (int m = 0; m < 2; ++m) {
        const u16* qp = qg + ((size_t)bh * SEQ + qbase + m * 16 + lr16) * HD + lg * 8;
        qf[m][0] = *(const bf8*)qp;
        qf[m][1] = *(const bf8*)(qp + 32);
    }

    const f4 zf = {0.f, 0.f, 0.f, 0.f};
    f4 Oa[2][4];
    float mr2[2][4], lp[2][4];          // running max (log2 dom), lane-partial l
#pragma unroll
    for (int m = 0; m < 2; ++m)
#pragma unroll
        for (int n = 0; n < 4; ++n) Oa[m][n] = zf;
#pragma unroll
    for (int m = 0; m < 2; ++m)
#pragma unroll
        for (int r = 0; r < 4; ++r) { mr2[m][r] = -1e30f; lp[m][r] = 0.f; }

    const u16* Kb = kg + (size_t)bh * SEQ * HD;
    const u16* Vb = vtg + (size_t)bh * HD * SEQ;
    u16* Pw = &Pl[w * QW * KS];

    float4 kvr[2], vvr[2];
    float mk2[2][4][4], mkn2[2][4][4];  // mask * log2(e), cur / next tile

    auto issue_kv = [&](int kv0) {
#pragma unroll
        for (int i = 0; i < 2; ++i) {
            const int c = i * 256 + t, a = c >> 3, cc = c & 7;
            kvr[i] = *(const float4*)&Kb[(size_t)(kv0 + a) * HD + cc * 8];
            vvr[i] = *(const float4*)&Vb[(size_t)a * SEQ + kv0 + cc * 8];
        }
    };
    auto write_kv = [&](int buf) {
#pragma unroll
        for (int i = 0; i < 2; ++i) {
            const int c = i * 256 + t, a = c >> 3, cc = c & 7;
            *(float4*)&Kl[buf][a * KS + cc * 8] = kvr[i];
            *(float4*)&Vl[buf][a * KS + cc * 8] = vvr[i];
        }
    };
    auto issue_mask = [&](float (&mm)[2][4][4], int kv0) {
#pragma unroll
        for (int m = 0; m < 2; ++m)
#pragma unroll
            for (int n = 0; n < 4; ++n)
#pragma unroll
                for (int r = 0; r < 4; ++r)
                    mm[m][n][r] = mask[(size_t)(qbase + m * 16 + lg * 4 + r) * SEQ
                                       + kv0 + n * 16 + lr16] * L2E;
    };

    issue_kv(0);
    issue_mask(mk2, 0);
    write_kv(0);
    issue_kv(64);
    issue_mask(mkn2, 64);
    __syncthreads();

    for (int kt = 0; kt < 32; ++kt) {
        const int cur = kt & 1;
        // ---- QK^T (K frags shared across the 2 m-blocks)
        f4 sc[2][4];
        __builtin_amdgcn_s_setprio(1);
#pragma unroll
        for (int n = 0; n < 4; ++n) {
            const bf8 k0 = *(const bf8*)&Kl[cur][(n * 16 + lr16) * KS + lg * 8];
            const bf8 k1 = *(const bf8*)&Kl[cur][(n * 16 + lr16) * KS + 32 + lg * 8];
#pragma unroll
            for (int m = 0; m < 2; ++m)
                sc[m][n] = MFMA(qf[m][1], k1, MFMA(qf[m][0], k0, zf));
        }
        __builtin_amdgcn_s_setprio(0);
        // ---- scale + mask, log2 domain
#pragma unroll
        for (int m = 0; m < 2; ++m)
#pragma unroll
            for (int n = 0; n < 4; ++n)
#pragma unroll
                for (int r = 0; r < 4; ++r)
                    sc[m][n][r] = fmaf(sc[m][n][r], C1, mk2[m][n][r]);
        // ---- lane-local row maxes; deferred-max trigger
        float lmax[2][4];
        bool need = false;
#pragma unroll
        for (int m = 0; m < 2; ++m)
#pragma unroll
            for (int r = 0; r < 4; ++r) {
                lmax[m][r] = fmaxf(fmaxf(sc[m][0][r], sc[m][1][r]),
                                   fmaxf(sc[m][2][r], sc[m][3][r]));
                need |= (lmax[m][r] > mr2[m][r] + 8.f);
            }
        if (__any(need)) {
#pragma unroll
            for (int m = 0; m < 2; ++m)
#pragma unroll
                for (int r = 0; r < 4; ++r) {
                    float mx = lmax[m][r];
#pragma unroll
                    for (int d = 1; d < 16; d <<= 1) mx = fmaxf(mx, __shfl_xor(mx, d));
                    const float mn = fmaxf(mr2[m][r], mx);
                    const float al = exp2f(mr2[m][r] - mn);
                    mr2[m][r] = mn;
                    lp[m][r] *= al;
#pragma unroll
                    for (int n = 0; n < 4; ++n) Oa[m][n][r] *= al;
                }
        }
        // ---- P = 2^(s - mr), lane-partial l, bf16, wave-private LDS roundtrip
#pragma unroll
        for (int m = 0; m < 2; ++m)
#pragma unroll
            for (int r = 0; r < 4; ++r) {
                float ps = 0.f;
#pragma unroll
                for (int n = 0; n < 4; ++n) {
                    const float p = exp2f(sc[m][n][r] - mr2[m][r]);  // <= 2^8
                    ps += p;
                    const __hip_bfloat16 hb = __float2bfloat16(p);
                    Pw[(m * 16 + lg * 4 + r) * KS + n * 16 + lr16] =
                        __builtin_bit_cast(u16, hb);
                }
                lp[m][r] += ps;
            }
        asm volatile("s_waitcnt lgkmcnt(0)" ::: "memory");
        bf8 pf[2][2];
#pragma unroll
        for (int m = 0; m < 2; ++m) {
            pf[m][0] = *(const bf8*)&Pw[(m * 16 + lr16) * KS + lg * 8];
            pf[m][1] = *(const bf8*)&Pw[(m * 16 + lr16) * KS + 32 + lg * 8];
        }
        // ---- PV (V frags shared across m-blocks)
        __builtin_amdgcn_s_setprio(1);
#pragma unroll
        for (int n = 0; n < 4; ++n) {
            const bf8 v0 = *(const bf8*)&Vl[cur][(n * 16 + lr16) * KS + lg * 8];
            const bf8 v1 = *(const bf8*)&Vl[cur][(n * 16 + lr16) * KS + 32 + lg * 8];
#pragma unroll
            for (int m = 0; m < 2; ++m) {
                Oa[m][n] = MFMA(pf[m][0], v0, Oa[m][n]);
                Oa[m][n] = MFMA(pf[m][1], v1, Oa[m][n]);
            }
        }
        __builtin_amdgcn_s_setprio(0);
        // ---- stage next tile; prefetch tile after
        if (kt < 31) {
            write_kv(cur ^ 1);
#pragma unroll
            for (int m = 0; m < 2; ++m)
#pragma unroll
                for (int n = 0; n < 4; ++n)
#pragma unroll
                    for (int r = 0; r < 4; ++r) mk2[m][n][r] = mkn2[m][n][r];
            if (kt < 30) {
                issue_kv((kt + 2) * 64);
                issue_mask(mkn2, (kt + 2) * 64);
            }
        }
        __syncthreads();
    }

    // ---- epilogue: final l reduce, O normalize, LDS stage, full-line stores
    float inv[2][4];
#pragma unroll
    for (int m = 0; m < 2; ++m)
#pragma unroll
        for (int r = 0; r < 4; ++r) {
            float s = lp[m][r];
#pragma unroll
            for (int d = 1; d < 16; d <<= 1) s += __shfl_xor(s, d);
            inv[m][r] = 1.f / s;
        }
    // Ol rows [w*32, w*32+32) == this wave's Pw region: no barrier needed yet
    u16* Ol = Pl;
#pragma unroll
    for (int m = 0; m < 2; ++m)
#pragma unroll
        for (int n = 0; n < 4; ++n)
#pragma unroll
            for (int r = 0; r < 4; ++r)
                Ol[(w * QW + m * 16 + lg * 4 + r) * KS + n * 16 + lr16] =
                    f2bf(Oa[m][n][r] * inv[m][r]);
    __syncthreads();
    {
        const int row = t >> 1, c0 = (t & 1) * 32;
        const u16* src = &Ol[row * KS + c0];
        u16* dstp = og + ((size_t)(b * SEQ + q0 + row)) * DM + h * HD + c0;
#pragma unroll
        for (int j = 0; j < 4; ++j)
            *(float4*)(dstp + j * 8) = *(const float4*)(src + j * 8);
    }
}

// ---------------------------------------------------------------------------
extern "C" void kernel_launch(void* const* d_in, const int* in_sizes, int n_in,
                              void* d_out, int out_size, void* d_ws, size_t ws_size,
                              hipStream_t stream) {
    const float* x     = (const float*)d_in[0];
    const float* mask  = (const float*)d_in[1];
    const float* W_qkv = (const float*)d_in[2];
    const float* b_qkv = (const float*)d_in[3];
    const float* W_out = (const float*)d_in[4];
    const float* b_out = (const float*)d_in[5];
    float* out = (float*)d_out;

    const size_t NQ = (size_t)BATCH * NH * SEQ * HD;      // 4M elems
    u16* ws  = (u16*)d_ws;
    u16* xb  = ws;
    u16* wqb = xb + (size_t)4096 * 1024;
    u16* wob = wqb + (size_t)3072 * 1024;
    u16* qb  = wob + (size_t)1024 * 1024;
    u16* kb  = qb + NQ;
    u16* vb  = kb + NQ;
    u16* vtb = vb + NQ;
    u16* ob  = vtb + NQ;

    cast_all<<<(N4_X + N4_WQ + N4_WO) / 256, 256, 0, stream>>>(x, W_qkv, W_out, xb, wqb, wob);
    gemm_bf16<0><<<dim3(24, 32), 256, 0, stream>>>(xb, wqb, b_qkv, qb, kb, vb, nullptr);
    v_transpose<<<dim3(32, 32), 256, 0, stream>>>(vb, vtb);
    flash_attn<<<dim3((SEQ / 128) * NH * BATCH), 256, 0, stream>>>(qb, kb, vtb, mask, ob);
    gemm_bf16<1><<<dim3(8, 32), 256, 0, stream>>>(ob, wob, b_out, nullptr, nullptr, nullptr, out);
}